// Round 11
// baseline (245.067 us; speedup 1.0000x reference)
//
#include <hip/hip_runtime.h>
#include <stdint.h>

// Problem dims (LSTMCell: B=4096, IN=1024, H=1024)
#define Bn 4096
#define INn 1024
#define Hn 1024
#define Kn 2048   // IN + H
#define Nn 4096   // 4*H

// GEMM tile: 128 batch x 256 W-rows (4 gates x 64 h), BK=64 (R8 proven-correct geometry)
#define BM 128
#define BN 256
#define BK 64
#define KT (Kn / BK)   // 32 K-tiles

typedef __attribute__((ext_vector_type(8))) short bf16x8;
typedef __attribute__((ext_vector_type(4))) float f32x4;
typedef __attribute__((ext_vector_type(4))) unsigned short us4;

// ---------- helpers ----------
__device__ __forceinline__ unsigned short f2bf(float f) {
  uint32_t u = __float_as_uint(f);
  u += 0x7fffu + ((u >> 16) & 1u);
  return (unsigned short)(u >> 16);
}

typedef __attribute__((address_space(3))) unsigned int as3_uint;
typedef const __attribute__((address_space(1))) unsigned int as1_uint;

__device__ __forceinline__ void gload16(const unsigned short* g, unsigned short* l) {
  __builtin_amdgcn_global_load_lds((as1_uint*)g, (as3_uint*)l, 16, 0, 0);
}

__device__ __forceinline__ float sigm(float x) { return 1.f / (1.f + __expf(-x)); }
__device__ __forceinline__ float tanh_fast(float x) { return 2.f / (1.f + __expf(-2.f * x)) - 1.f; }

// ---------- kernel 1: fused f32->bf16 pack ----------
__global__ void pack_all(const float* __restrict__ x, const float* __restrict__ h,
                         const float* __restrict__ W,
                         unsigned short* __restrict__ Abf, unsigned short* __restrict__ Wbf) {
  const long XQ = (long)Bn * INn / 4;
  const long WQ = (long)Nn * Kn / 4;
  const long total = XQ + XQ + WQ;
  const long stride = (long)gridDim.x * blockDim.x;
  for (long q = (long)blockIdx.x * blockDim.x + threadIdx.x; q < total; q += stride) {
    float4 v;
    unsigned short* dst;
    if (q < XQ) {
      long e = q << 2;
      v = *(const float4*)(x + e);
      dst = Abf + ((long)(e >> 10) * Kn) + (e & 1023);
    } else if (q < 2 * XQ) {
      long e = (q - XQ) << 2;
      v = *(const float4*)(h + e);
      dst = Abf + ((long)(e >> 10) * Kn) + INn + (e & 1023);
    } else {
      long e = (q - 2 * XQ) << 2;
      v = *(const float4*)(W + e);
      dst = Wbf + e;
    }
    us4 o;
    o.x = f2bf(v.x); o.y = f2bf(v.y); o.z = f2bf(v.z); o.w = f2bf(v.w);
    *(us4*)dst = o;
  }
}

// ---------- kernel 2: fused GEMM + LSTM epilogue, 4-phase read-ahead pipeline ----------
// R9 post-mortem: 72% of tile time was stall (reads->MFMA dependency + drain at 1 blk/CU).
// Fix: ds_reads issued ONE PHASE AHEAD of their MFMAs (single-assignment named regs),
// so MFMA never waits on LDS latency; compiler emits counted lgkmcnt. Per tile:
//   ph0: stage A(t+2);   read a23k0;        MFMA m0,m1 x bk0 (k0)
//   ph1: stage B01(t+2); read a01k1,bk1;    MFMA m2,m3 x bk0 (k0)
//   ph2: stage B23(t+2); read a23k1;        MFMA m0,m1 x bk1 (k1); vmcnt(6)
//   ph3:                 read a01k0',bk0' (tile t+1 buf); MFMA m2,m3 x bk1 (k1)
// 3-buffer rotation + vmcnt(6) ledger and swizzle are unchanged from R8 (ran correct,
// conflicts==0). vmcnt(6) sits before the ph2->ph3 barrier: own-drain + barrier =>
// all waves' tile-(t+1) loads visible before ph3 reads them. Tails: t=30 vmcnt(0),
// t=31 skips next-tile reads.
#define STAGE_A(t_, b_) do {                                                     \
    const int k0_ = (t_) * BK;                                                   \
    gload16(Ag + (long)(brow + srow) * Kn + k0_ + scol,                          \
            &bufA[b_][srow * BK + sc8 * 8]);                                     \
    gload16(Ag + (long)(brow + 64 + srow) * Kn + k0_ + scol,                     \
            &bufA[b_][(64 + srow) * BK + sc8 * 8]);                              \
  } while (0)
#define STAGE_B(t_, b_, j_) do {                                                 \
    const int k0_ = (t_) * BK;                                                   \
    const int rb_ = (j_) * 64 + srow;                                            \
    const int grow_ = ((rb_ >> 4) & 3) * Hn + h0 + ((rb_ >> 6) << 4) + (rb_ & 15);\
    gload16(Wg + (long)grow_ * Kn + k0_ + scol,                                  \
            &bufB[b_][rb_ * BK + sc8 * 8]);                                      \
  } while (0)
#define FENCE() do { asm volatile("" ::: "memory"); __builtin_amdgcn_sched_barrier(0); } while (0)
// 8 MFMAs: rows (ml, ml+1) x 4 gate-frags with A pair ap, B set bs
#define MFMA8(ml, ap, bs) do {                                                   \
    _Pragma("unroll")                                                            \
    for (int n = 0; n < 4; ++n) {                                                \
      acc[(ml)][n]     = __builtin_amdgcn_mfma_f32_16x16x32_bf16(ap[0], bs[n], acc[(ml)][n], 0, 0, 0);     \
      acc[(ml) + 1][n] = __builtin_amdgcn_mfma_f32_16x16x32_bf16(ap[1], bs[n], acc[(ml) + 1][n], 0, 0, 0); \
    }                                                                            \
  } while (0)

__global__ void __launch_bounds__(512, 2)
lstm_gemm_fused(const unsigned short* __restrict__ Ag,
                const unsigned short* __restrict__ Wg,
                const float* __restrict__ c_prev,
                const float* __restrict__ bias,
                float* __restrict__ out) {
  __shared__ unsigned short bufA[3][BM * BK];   // 3 x 16 KB
  __shared__ unsigned short bufB[3][BN * BK];   // 3 x 32 KB  (144 KB)

  const int tid = threadIdx.x;
  const int lane = tid & 63;
  const int wid = tid >> 6;
  const int wr = wid >> 2;            // 0..1 : batch 64-half
  const int wc = wid & 3;             // 0..3 : h 16-group
  const int brow = blockIdx.y * BM;
  const int h0 = blockIdx.x * 64;

  // staging map (verified R5/R8): LDS dest = wave-uniform + lane*16; swizzled global src
  const int srow = tid >> 3;                      // 0..63
  const int sc8 = tid & 7;                        // dest chunk 0..7
  const int scol = ((sc8 ^ (srow & 7)) * 8);      // pre-swizzled source col

  // fragment read offsets (inverse swizzle)
  const int l15 = lane & 15;
  const int s7 = l15 & 7;
  const int cA = lane >> 4;                       // 0..3
  const int aOff0 = (wr * 64 + l15) * BK + ((cA) ^ s7) * 8;
  const int aOff1 = (wr * 64 + l15) * BK + ((cA + 4) ^ s7) * 8;
  const int bOff0 = (wc * 64 + l15) * BK + ((cA) ^ s7) * 8;
  const int bOff1 = (wc * 64 + l15) * BK + ((cA + 4) ^ s7) * 8;

  f32x4 acc[4][4] = {};   // acc[m][n]: m = batch frag, n = GATE
  bf16x8 a01k0[2], a23k0[2], a01k1[2], a23k1[2], bk0[4], bk1[4];

  // prologue: stage tiles 0,1 (6 gloads each); drain tile 0; first operand reads
  STAGE_A(0, 0); STAGE_B(0, 0, 0); STAGE_B(0, 0, 1); STAGE_B(0, 0, 2); STAGE_B(0, 0, 3);
  STAGE_A(1, 1); STAGE_B(1, 1, 0); STAGE_B(1, 1, 1); STAGE_B(1, 1, 2); STAGE_B(1, 1, 3);
  asm volatile("s_waitcnt vmcnt(6)" ::: "memory");
  __builtin_amdgcn_s_barrier();
  FENCE();
  {
    const unsigned short* As = bufA[0];
    const unsigned short* Bs = bufB[0];
    a01k0[0] = *(const bf16x8*)&As[aOff0];
    a01k0[1] = *(const bf16x8*)&As[aOff0 + 16 * BK];
#pragma unroll
    for (int n = 0; n < 4; ++n) bk0[n] = *(const bf16x8*)&Bs[bOff0 + n * 16 * BK];
  }

  for (int t = 0; t < KT; ++t) {
    const int bi = t % 3;
    const int sb = (t + 2) % 3;
    const int bn = (t + 1) % 3;
    const bool st = (t + 2) < KT;
    const unsigned short* As = bufA[bi];
    const unsigned short* Bs = bufB[bi];

    // ---- phase 0 ----
    if (st) STAGE_A(t + 2, sb);
    a23k0[0] = *(const bf16x8*)&As[aOff0 + 32 * BK];
    a23k0[1] = *(const bf16x8*)&As[aOff0 + 48 * BK];
    __builtin_amdgcn_s_setprio(1);
    MFMA8(0, a01k0, bk0);
    __builtin_amdgcn_s_setprio(0);
    __builtin_amdgcn_s_barrier();
    FENCE();

    // ---- phase 1 ----
    if (st) { STAGE_B(t + 2, sb, 0); STAGE_B(t + 2, sb, 1); }
    a01k1[0] = *(const bf16x8*)&As[aOff1];
    a01k1[1] = *(const bf16x8*)&As[aOff1 + 16 * BK];
#pragma unroll
    for (int n = 0; n < 4; ++n) bk1[n] = *(const bf16x8*)&Bs[bOff1 + n * 16 * BK];
    __builtin_amdgcn_s_setprio(1);
    MFMA8(2, a23k0, bk0);
    __builtin_amdgcn_s_setprio(0);
    __builtin_amdgcn_s_barrier();
    FENCE();

    // ---- phase 2 ----
    if (st) { STAGE_B(t + 2, sb, 2); STAGE_B(t + 2, sb, 3); }
    a23k1[0] = *(const bf16x8*)&As[aOff1 + 32 * BK];
    a23k1[1] = *(const bf16x8*)&As[aOff1 + 48 * BK];
    __builtin_amdgcn_s_setprio(1);
    MFMA8(0, a01k1, bk1);
    __builtin_amdgcn_s_setprio(0);
    if (t < KT - 2) asm volatile("s_waitcnt vmcnt(6)" ::: "memory");
    else            asm volatile("s_waitcnt vmcnt(0)" ::: "memory");
    __builtin_amdgcn_s_barrier();
    FENCE();

    // ---- phase 3: read NEXT tile's first operands ----
    if (t + 1 < KT) {
      const unsigned short* An = bufA[bn];
      const unsigned short* Bsn = bufB[bn];
      a01k0[0] = *(const bf16x8*)&An[aOff0];
      a01k0[1] = *(const bf16x8*)&An[aOff0 + 16 * BK];
#pragma unroll
      for (int n = 0; n < 4; ++n) bk0[n] = *(const bf16x8*)&Bsn[bOff0 + n * 16 * BK];
    }
    __builtin_amdgcn_s_setprio(1);
    MFMA8(2, a23k1, bk1);
    __builtin_amdgcn_s_setprio(0);
    __builtin_amdgcn_s_barrier();
    FENCE();
  }

  // ---- fused LSTM epilogue, in-register ----
  // C/D layout (verified m89/m91): col = lane&15 (h), row = (lane>>4)*4 + j
  const int hcol = h0 + wc * 16 + l15;
  const float bf_ = bias[hcol];
  const float bi_ = bias[Hn + hcol];
  const float bg_ = bias[2 * Hn + hcol];
  const float bo_ = bias[3 * Hn + hcol];
  const int rbase = brow + wr * 64 + ((lane >> 4) << 2);
  const long BH = (long)Bn * Hn;
#pragma unroll
  for (int m = 0; m < 4; ++m) {
#pragma unroll
    for (int j = 0; j < 4; ++j) {
      const long r = rbase + m * 16 + j;
      const float f = sigm(acc[m][0][j] + bf_);
      const float i_ = sigm(acc[m][1][j] + bi_);
      const float g = tanh_fast(acc[m][2][j] + bg_);
      const float o = sigm(acc[m][3][j] + bo_);
      const float cp = c_prev[r * Hn + hcol];
      const float ct = f * cp + i_ * g;
      out[r * Hn + hcol] = o * tanh_fast(ct);   // h_t
      out[BH + r * Hn + hcol] = ct;             // c_t
    }
  }
}

// ---------- launch ----------
extern "C" void kernel_launch(void* const* d_in, const int* in_sizes, int n_in,
                              void* d_out, int out_size, void* d_ws, size_t ws_size,
                              hipStream_t stream) {
  const float* x      = (const float*)d_in[0];
  const float* h_prev = (const float*)d_in[1];
  const float* c_prev = (const float*)d_in[2];
  const float* W      = (const float*)d_in[3];
  const float* bias   = (const float*)d_in[4];
  float* out = (float*)d_out;

  unsigned short* Abf = (unsigned short*)d_ws;
  unsigned short* Wbf = Abf + (long)Bn * Kn;

  pack_all<<<2048, 256, 0, stream>>>(x, h_prev, W, Abf, Wbf);

  dim3 grid(Hn / 64, Bn / BM);   // (16, 32)
  lstm_gemm_fused<<<grid, 512, 0, stream>>>(Abf, Wbf, c_prev, bias, out);
}